// Round 8
// baseline (387.614 us; speedup 1.0000x reference)
//
#include <hip/hip_runtime.h>

#define BATCH   1024
#define MAXLEN  200
#define KCAPS   8
#define INU     256
#define OUTU    256
#define NEGPAD  -65535.0f
#define HSTR    264   // Hi LDS row stride (floats)

typedef _Float16 f16;
typedef _Float16 f16x8 __attribute__((ext_vector_type(8)));
typedef float    f32x4 __attribute__((ext_vector_type(4)));

// ---------------- prep: Bcur copy + S split to hi/lo fp16 (packed frag order)
__global__ void k_prep(const float* __restrict__ S, const float* __restrict__ Bm,
                       f16* __restrict__ Shi, f16* __restrict__ Slo,
                       float* __restrict__ Bcur) {
    int idx = blockIdx.x * 256 + threadIdx.x;    // 0 .. 65535
    if (idx < KCAPS * MAXLEN) Bcur[idx] = Bm[idx];
    int j    = idx & 7;
    int lane = (idx >> 3) & 63;
    int nf   = (idx >> 9) & 15;
    int ks   = idx >> 13;
    int k = ks * 32 + (lane >> 4) * 8 + j;
    int n = nf * 16 + (lane & 15);
    float v = S[k * OUTU + n];
    f16 h = (f16)v;
    Shi[idx] = h;
    Slo[idx] = (f16)(v - (float)h);
}

// ---------------- projection: reg-staged, BN=256, no LDS, no barriers ------
// 3200 blocks x 256 thr (4 waves). Block tile 64x256: all waves share the
// same 64 A-rows (read EXACTLY once from HBM per block; L1 serves the 4x
// intra-block reuse, no cross-XCD sharing). Wave tile 64x64. Manual
// distance-1 A-prefetch in named regs; convert AFTER the MFMA block so the
// 48 MFMAs cover the load latency. B (L2-resident) hoisted by compiler.
__global__ __launch_bounds__(256, 3) void k_project_mfma(const float* __restrict__ A,
                                                         const f16* __restrict__ Shi,
                                                         const f16* __restrict__ Slo,
                                                         float* __restrict__ C) {
    const int tid  = threadIdx.x;
    const int wave = tid >> 6, lane = tid & 63;
    const int r15 = lane & 15, q = lane >> 4;
    const size_t m0 = (size_t)blockIdx.x * 64;
    const int n0 = wave * 64;

    const float* ab = A + (m0 + r15) * INU + q * 8;               // + mf*4096 + ks*32
    const f16* sh = Shi + (size_t)(wave * 4) * 512 + lane * 8;    // + ks*8192 + nf*512
    const f16* sl = Slo + (size_t)(wave * 4) * 512 + lane * 8;

    f32x4 acc[4][4];
    #pragma unroll
    for (int a = 0; a < 4; a++)
        #pragma unroll
        for (int b = 0; b < 4; b++)
            acc[a][b] = (f32x4){0.f, 0.f, 0.f, 0.f};

    // prologue: load + convert A-frags for ks=0
    f16x8 fah[4], fal[4];
    #pragma unroll
    for (int mf = 0; mf < 4; mf++) {
        const float* ap = ab + mf * 4096;
        f32x4 a0 = *reinterpret_cast<const f32x4*>(ap);
        f32x4 a1 = *reinterpret_cast<const f32x4*>(ap + 4);
        #pragma unroll
        for (int j = 0; j < 4; j++) {
            f16 t = (f16)a0[j]; fah[mf][j] = t; fal[mf][j] = (f16)(a0[j] - (float)t);
        }
        #pragma unroll
        for (int j = 0; j < 4; j++) {
            f16 t = (f16)a1[j]; fah[mf][4 + j] = t; fal[mf][4 + j] = (f16)(a1[j] - (float)t);
        }
    }

    #pragma unroll
    for (int ks = 0; ks < 8; ks++) {
        // issue next K-slice A loads first (HBM stream, longest latency)
        f32x4 na0[4], na1[4];
        if (ks < 7) {
            #pragma unroll
            for (int mf = 0; mf < 4; mf++) {
                const float* ap = ab + mf * 4096 + (ks + 1) * 32;
                na0[mf] = *reinterpret_cast<const f32x4*>(ap);
                na1[mf] = *reinterpret_cast<const f32x4*>(ap + 4);
            }
        }
        // B frags for this K-slice (L2-resident; compiler hoists across iters)
        f16x8 bh[4], bl[4];
        #pragma unroll
        for (int nf = 0; nf < 4; nf++) {
            bh[nf] = *reinterpret_cast<const f16x8*>(sh + ks * 8192 + nf * 512);
            bl[nf] = *reinterpret_cast<const f16x8*>(sl + ks * 8192 + nf * 512);
        }
        // 48 MFMAs on current frags (covers the na-load latency)
        #pragma unroll
        for (int mf = 0; mf < 4; mf++)
            #pragma unroll
            for (int nf = 0; nf < 4; nf++) {
                acc[mf][nf] = __builtin_amdgcn_mfma_f32_16x16x32_f16(fah[mf], bh[nf], acc[mf][nf], 0, 0, 0);
                acc[mf][nf] = __builtin_amdgcn_mfma_f32_16x16x32_f16(fal[mf], bh[nf], acc[mf][nf], 0, 0, 0);
                acc[mf][nf] = __builtin_amdgcn_mfma_f32_16x16x32_f16(fah[mf], bl[nf], acc[mf][nf], 0, 0, 0);
            }
        // convert next slice into the frag registers
        if (ks < 7) {
            #pragma unroll
            for (int mf = 0; mf < 4; mf++) {
                #pragma unroll
                for (int j = 0; j < 4; j++) {
                    f16 t = (f16)na0[mf][j]; fah[mf][j] = t; fal[mf][j] = (f16)(na0[mf][j] - (float)t);
                }
                #pragma unroll
                for (int j = 0; j < 4; j++) {
                    f16 t = (f16)na1[mf][j]; fah[mf][4 + j] = t; fal[mf][4 + j] = (f16)(na1[mf][j] - (float)t);
                }
            }
        }
    }

    #pragma unroll
    for (int mf = 0; mf < 4; mf++) {
        size_t rbase = m0 + mf * 16 + q * 4;
        #pragma unroll
        for (int nf = 0; nf < 4; nf++) {
            int c = n0 + nf * 16 + r15;
            #pragma unroll
            for (int r = 0; r < 4; r++)
                C[(rbase + r) * OUTU + c] = acc[mf][nf][r];
        }
    }
}

// ---------------- routing iteration (512 threads, len-bounded pass 1) ------
__global__ __launch_bounds__(512) void k_route(const float* __restrict__ Bcur,
                                               const int*   __restrict__ seq_len,
                                               const float* __restrict__ low_new,
                                               float*       __restrict__ partials,
                                               float*       __restrict__ out,
                                               int do_delta, int do_out) {
    __shared__ float Wl[KCAPS * MAXLEN];   // 6.4 KB
    __shared__ float Sl[KCAPS * 256];      // 8 KB  partial-hk slab
    __shared__ float Hi[16 * HSTR];        // 16.9 KB
    const int b   = blockIdx.x;
    const int tid = threadIdx.x;
    const int len = seq_len[b];

    for (int i = tid; i < KCAPS * MAXLEN; i += 512) Wl[i] = Bcur[i];
    for (int i = tid; i < 16 * HSTR; i += 512) Hi[i] = 0.f;
    __syncthreads();

    // masked softmax: one 64-lane wave per k
    {
        const int k  = tid >> 6;
        const int ln = tid & 63;
        float m = -3.4e38f;
        for (int l = ln; l < MAXLEN; l += 64) {
            float v = (l < len) ? Wl[k * MAXLEN + l] : NEGPAD;
            m = fmaxf(m, v);
        }
        #pragma unroll
        for (int off = 32; off >= 1; off >>= 1) m = fmaxf(m, __shfl_xor(m, off));
        float ssum = 0.f;
        for (int l = ln; l < MAXLEN; l += 64) {
            float v = (l < len) ? Wl[k * MAXLEN + l] : NEGPAD;
            ssum += __expf(v - m);
        }
        #pragma unroll
        for (int off = 32; off >= 1; off >>= 1) ssum += __shfl_xor(ssum, off);
        float inv = 1.f / ssum;
        for (int l = ln; l < MAXLEN; l += 64) {
            float v = (l < len) ? Wl[k * MAXLEN + l] : NEGPAD;
            Wl[k * MAXLEN + l] = __expf(v - m) * inv;
        }
    }
    __syncthreads();

    // pass 1: o = tid&255; lg groups interleave 4-l chunks; W==0 for l>=len (len>0)
    const float* lb = low_new + (size_t)b * (MAXLEN * OUTU);
    const int o   = tid & 255;
    const int lg  = tid >> 8;
    const int lim = (len == 0) ? MAXLEN : len;   // len==0 -> uniform W, need all l
    float hk[KCAPS];
    #pragma unroll
    for (int k = 0; k < KCAPS; k++) hk[k] = 0.f;
    for (int l4 = lg * 4; l4 < lim; l4 += 8) {   // max l4=196, reads l4..l4+3 <= 199: safe
        float v0 = lb[(l4 + 0) * OUTU + o];
        float v1 = lb[(l4 + 1) * OUTU + o];
        float v2 = lb[(l4 + 2) * OUTU + o];
        float v3 = lb[(l4 + 3) * OUTU + o];
        #pragma unroll
        for (int k = 0; k < KCAPS; k++) {
            const float4 w = *reinterpret_cast<const float4*>(&Wl[k * MAXLEN + l4]);
            hk[k] = fmaf(w.x, v0, hk[k]);
            hk[k] = fmaf(w.y, v1, hk[k]);
            hk[k] = fmaf(w.z, v2, hk[k]);
            hk[k] = fmaf(w.w, v3, hk[k]);
        }
    }
    if (lg == 1) {
        #pragma unroll
        for (int k = 0; k < KCAPS; k++) Sl[k * 256 + o] = hk[k];
    }
    __syncthreads();

    float scale = 0.f;
    if (lg == 0) {
        float n = 0.f;
        #pragma unroll
        for (int k = 0; k < KCAPS; k++) {
            hk[k] += Sl[k * 256 + o];
            n = fmaf(hk[k], hk[k], n);
        }
        scale = n / (1.f + n) * (1.f / sqrtf(n + 1e-9f));
        if (do_out) {
            #pragma unroll
            for (int k = 0; k < KCAPS; k++)
                out[((size_t)b * KCAPS + k) * OUTU + o] = scale * hk[k];
        }
    }
    if (!do_delta) return;

    if (lg == 0) {
        #pragma unroll
        for (int k = 0; k < KCAPS; k++) Hi[k * HSTR + o] = scale * hk[k];
    }
    __syncthreads();

    // pass 2 (MFMA): delta_T[l][k] = sum_o low[l][o] * high[k][o]; 13 M-frags over 8 waves
    const int wave = tid >> 6, lane = tid & 63;
    const int nfr = (wave < 5) ? 2 : 1;
    f32x4 acc2[2];
    acc2[0] = (f32x4){0.f, 0.f, 0.f, 0.f};
    acc2[1] = (f32x4){0.f, 0.f, 0.f, 0.f};

    for (int ks = 0; ks < 8; ks++) {
        const int ob = ks * 32 + ((lane >> 4) * 8);
        f32x4 h0 = *reinterpret_cast<const f32x4*>(&Hi[(lane & 15) * HSTR + ob]);
        f32x4 h1 = *reinterpret_cast<const f32x4*>(&Hi[(lane & 15) * HSTR + ob + 4]);
        f16x8 bh, bl;
        #pragma unroll
        for (int j = 0; j < 4; j++) {
            f16 t = (f16)h0[j]; bh[j] = t; bl[j] = (f16)(h0[j] - (float)t);
        }
        #pragma unroll
        for (int j = 0; j < 4; j++) {
            f16 t = (f16)h1[j]; bh[4 + j] = t; bl[4 + j] = (f16)(h1[j] - (float)t);
        }
        for (int mi = 0; mi < nfr; mi++) {
            const int mf = wave + mi * 8;
            const int l  = mf * 16 + (lane & 15);      // may exceed 199: garbage row, unwritten
            const float* ap = lb + (size_t)l * OUTU + ob;
            float4 v0 = *reinterpret_cast<const float4*>(ap);
            float4 v1 = *reinterpret_cast<const float4*>(ap + 4);
            f16x8 ah, al;
            ah[0] = (f16)v0.x; al[0] = (f16)(v0.x - (float)ah[0]);
            ah[1] = (f16)v0.y; al[1] = (f16)(v0.y - (float)ah[1]);
            ah[2] = (f16)v0.z; al[2] = (f16)(v0.z - (float)ah[2]);
            ah[3] = (f16)v0.w; al[3] = (f16)(v0.w - (float)ah[3]);
            ah[4] = (f16)v1.x; al[4] = (f16)(v1.x - (float)ah[4]);
            ah[5] = (f16)v1.y; al[5] = (f16)(v1.y - (float)ah[5]);
            ah[6] = (f16)v1.z; al[6] = (f16)(v1.z - (float)ah[6]);
            ah[7] = (f16)v1.w; al[7] = (f16)(v1.w - (float)ah[7]);
            acc2[mi] = __builtin_amdgcn_mfma_f32_16x16x32_f16(ah, bh, acc2[mi], 0, 0, 0);
            acc2[mi] = __builtin_amdgcn_mfma_f32_16x16x32_f16(al, bh, acc2[mi], 0, 0, 0);
            acc2[mi] = __builtin_amdgcn_mfma_f32_16x16x32_f16(ah, bl, acc2[mi], 0, 0, 0);
        }
    }
    const int kcol = lane & 15;
    if (kcol < KCAPS) {
        for (int mi = 0; mi < nfr; mi++) {
            const int mf = wave + mi * 8;
            const int lbase = mf * 16 + ((lane >> 4) * 4);
            #pragma unroll
            for (int r = 0; r < 4; r++) {
                const int l = lbase + r;
                if (l < MAXLEN)
                    partials[(size_t)(kcol * MAXLEN + l) * BATCH + b] = acc2[mi][r];
            }
        }
    }
}

// ---------------- B update ----------------
__global__ __launch_bounds__(256) void k_update(const float* __restrict__ partials,
                                                float* __restrict__ Bcur) {
    __shared__ float red[256];
    const int i   = blockIdx.x;
    const int tid = threadIdx.x;
    float s = 0.f;
    #pragma unroll
    for (int j = 0; j < BATCH / 256; j++) s += partials[(size_t)i * BATCH + tid + j * 256];
    red[tid] = s;
    __syncthreads();
    for (int st = 128; st > 0; st >>= 1) {
        if (tid < st) red[tid] += red[tid + st];
        __syncthreads();
    }
    if (tid == 0) Bcur[i] += red[0];
}

extern "C" void kernel_launch(void* const* d_in, const int* in_sizes, int n_in,
                              void* d_out, int out_size, void* d_ws, size_t ws_size,
                              hipStream_t stream) {
    const float* low = (const float*)d_in[0];
    const float* S   = (const float*)d_in[1];
    const float* Bm  = (const float*)d_in[2];
    const int*   seq = (const int*)d_in[3];
    float* out = (float*)d_out;

    char* ws = (char*)d_ws;
    float* low_new  = (float*)ws;                              // 209,715,200 B
    float* Bcur     = (float*)(ws + 209715200);                // 6,400 B
    float* partials = (float*)(ws + 209721600);                // 6,553,600 B
    f16* Shi = (f16*)(ws + 209721600);                         // aliases partials (projection-only)
    f16* Slo = (f16*)(ws + 209721600 + 131072);

    k_prep<<<256, 256, 0, stream>>>(S, Bm, Shi, Slo, Bcur);
    k_project_mfma<<<3200, 256, 0, stream>>>(low, Shi, Slo, low_new);
    for (int it = 0; it < 3; it++) {
        int last = (it == 2);
        k_route<<<BATCH, 512, 0, stream>>>(Bcur, seq, low_new, partials, out,
                                           last ? 0 : 1, last ? 1 : 0);
        if (!last) k_update<<<KCAPS * MAXLEN, 256, 0, stream>>>(partials, Bcur);
    }
}

// Round 9
// 342.318 us; speedup vs baseline: 1.1323x; 1.1323x over previous
//
#include <hip/hip_runtime.h>

#define BATCH   1024
#define MAXLEN  200
#define KCAPS   8
#define INU     256
#define OUTU    256
#define NEGPAD  -65535.0f
#define HSTR    264   // Hi LDS row stride (floats)

typedef _Float16 f16;
typedef _Float16 f16x8 __attribute__((ext_vector_type(8)));
typedef float    f32x4 __attribute__((ext_vector_type(4)));

__device__ __forceinline__ void gload16(const void* g, void* l) {
    __builtin_amdgcn_global_load_lds(
        (const __attribute__((address_space(1))) void*)g,
        (__attribute__((address_space(3))) void*)l, 16, 0, 0);
}

// ---------------- prep: Bcur copy + S split to hi/lo fp16 (packed frag order)
__global__ void k_prep(const float* __restrict__ S, const float* __restrict__ Bm,
                       f16* __restrict__ Shi, f16* __restrict__ Slo,
                       float* __restrict__ Bcur) {
    int idx = blockIdx.x * 256 + threadIdx.x;    // 0 .. 65535
    if (idx < KCAPS * MAXLEN) Bcur[idx] = Bm[idx];
    int j    = idx & 7;
    int lane = (idx >> 3) & 63;
    int nf   = (idx >> 9) & 15;
    int ks   = idx >> 13;
    int k = ks * 32 + (lane >> 4) * 8 + j;
    int n = nf * 16 + (lane & 15);
    float v = S[k * OUTU + n];
    f16 h = (f16)v;
    Shi[idx] = h;
    Slo[idx] = (f16)(v - (float)h);
}

// ---------------- projection: T3/T4 pattern — gload_lds + counted vmcnt +
// RAW s_barrier (no drain). 3200 blocks x 256 thr (4 waves). Block tile
// 64x256 (A read once per block); wave tile 64x64. Double-buffered 8KB A
// tiles; B frags prefetched 1 K-step ahead so vmcnt(10) retires exactly
// {A-DMA(ks), B(ks)} and keeps {A-DMA(ks+1), B(ks+1)} in flight ACROSS the
// barrier. Output written as planar f16 hi/lo (bit-identical pass-2 frags).
__global__ __launch_bounds__(256, 3) void k_project_mfma(const float* __restrict__ A,
                                                         const f16* __restrict__ Shi,
                                                         const f16* __restrict__ Slo,
                                                         f16* __restrict__ CH,
                                                         f16* __restrict__ CL) {
    __shared__ float Af[2][64 * 32];   // 2 x 8 KB
    const int tid  = threadIdx.x;
    const int wave = tid >> 6, lane = tid & 63;
    const int r15 = lane & 15, q = lane >> 4;
    const size_t m0 = (size_t)blockIdx.x * 64;
    const int n0 = wave * 64;

    // staging: 2 x (256 thr x 16B) = 8KB tile (64 rows x 128B). LDS linear;
    // source col pre-swizzled so swizzled READS hit distinct banks (rule 21).
    const int srow = tid >> 3;                                   // +32 for chunk 1
    const int scol = ((tid & 7) * 16) ^ (((tid >> 3) & 7) << 4); // involution
    const char* gA = (const char*)(A + (m0 + srow) * INU) + scol; // +ks*128; +32768 chunk1

    const f16* sh = Shi + (size_t)(wave * 4) * 512 + lane * 8;   // +ks*8192 +nf*512
    const f16* sl = Slo + (size_t)(wave * 4) * 512 + lane * 8;

    // read-side swizzle
    const int rsw  = (lane & 7) << 4;     // (row&7)<<4, row = mf*16 + r15
    const int cby0 = (q * 32) ^ rsw;
    const int cby1 = (q * 32 + 16) ^ rsw;

    f32x4 acc[4][4];
    #pragma unroll
    for (int a = 0; a < 4; a++)
        #pragma unroll
        for (int b = 0; b < 4; b++)
            acc[a][b] = (f32x4){0.f, 0.f, 0.f, 0.f};

    f16x8 bh[2][4], bl[2][4];

    // prologue: issue A-DMA(0) + B(0) loads (10 vmem ops)
    gload16(gA,         &Af[0][tid * 4]);
    gload16(gA + 32768, &Af[0][1024 + tid * 4]);
    #pragma unroll
    for (int nf = 0; nf < 4; nf++) {
        bh[0][nf] = *reinterpret_cast<const f16x8*>(sh + nf * 512);
        bl[0][nf] = *reinterpret_cast<const f16x8*>(sl + nf * 512);
    }

    #pragma unroll
    for (int ks = 0; ks < 8; ks++) {
        const int cur = ks & 1;
        if (ks < 7) {
            // issue next tile's A-DMA + B loads (10 newest vmem ops)
            gload16(gA + (ks + 1) * 128,         &Af[cur ^ 1][tid * 4]);
            gload16(gA + (ks + 1) * 128 + 32768, &Af[cur ^ 1][1024 + tid * 4]);
            #pragma unroll
            for (int nf = 0; nf < 4; nf++) {
                bh[cur ^ 1][nf] = *reinterpret_cast<const f16x8*>(sh + (ks + 1) * 8192 + nf * 512);
                bl[cur ^ 1][nf] = *reinterpret_cast<const f16x8*>(sl + (ks + 1) * 8192 + nf * 512);
            }
            // retire {A-DMA(ks), B(ks)}; keep this iter's 10 in flight
            asm volatile("s_waitcnt vmcnt(10)" ::: "memory");
        } else {
            asm volatile("s_waitcnt vmcnt(0)" ::: "memory");
        }
        __builtin_amdgcn_s_barrier();          // RAW barrier: no vmem drain
        __builtin_amdgcn_sched_barrier(0);

        // A frags from LDS (swizzled), split hi/lo, 48 MFMAs
        const char* ab = (const char*)&Af[cur][0];
        #pragma unroll
        for (int mf = 0; mf < 4; mf++) {
            const int row = mf * 16 + r15;
            f32x4 a0 = *reinterpret_cast<const f32x4*>(ab + row * 128 + cby0);
            f32x4 a1 = *reinterpret_cast<const f32x4*>(ab + row * 128 + cby1);
            f16x8 ah, al;
            #pragma unroll
            for (int j = 0; j < 4; j++) {
                f16 t = (f16)a0[j]; ah[j] = t; al[j] = (f16)(a0[j] - (float)t);
            }
            #pragma unroll
            for (int j = 0; j < 4; j++) {
                f16 t = (f16)a1[j]; ah[4 + j] = t; al[4 + j] = (f16)(a1[j] - (float)t);
            }
            #pragma unroll
            for (int nf = 0; nf < 4; nf++) {
                acc[mf][nf] = __builtin_amdgcn_mfma_f32_16x16x32_f16(ah, bh[cur][nf], acc[mf][nf], 0, 0, 0);
                acc[mf][nf] = __builtin_amdgcn_mfma_f32_16x16x32_f16(al, bh[cur][nf], acc[mf][nf], 0, 0, 0);
                acc[mf][nf] = __builtin_amdgcn_mfma_f32_16x16x32_f16(ah, bl[cur][nf], acc[mf][nf], 0, 0, 0);
            }
        }
        __builtin_amdgcn_s_barrier();          // reads done before next DMA overwrites
    }

    // epilogue: write planar f16 hi/lo
    #pragma unroll
    for (int mf = 0; mf < 4; mf++) {
        size_t rbase = m0 + mf * 16 + q * 4;
        #pragma unroll
        for (int nf = 0; nf < 4; nf++) {
            int c = n0 + nf * 16 + r15;
            #pragma unroll
            for (int r = 0; r < 4; r++) {
                float v = acc[mf][nf][r];
                f16 h = (f16)v;
                size_t idx = (rbase + r) * OUTU + c;
                CH[idx] = h;
                CL[idx] = (f16)(v - (float)h);
            }
        }
    }
}

// ---------------- routing iteration (512 threads, planar f16 hi/lo low_new) -
__global__ __launch_bounds__(512) void k_route(const float* __restrict__ Bcur,
                                               const int*   __restrict__ seq_len,
                                               const f16*   __restrict__ LH,
                                               const f16*   __restrict__ LL,
                                               float*       __restrict__ partials,
                                               float*       __restrict__ out,
                                               int do_delta, int do_out) {
    __shared__ float Wl[KCAPS * MAXLEN];   // 6.4 KB
    __shared__ float Sl[KCAPS * 256];      // 8 KB  partial-hk slab
    __shared__ float Hi[16 * HSTR];        // 16.9 KB
    const int b   = blockIdx.x;
    const int tid = threadIdx.x;
    const int len = seq_len[b];

    for (int i = tid; i < KCAPS * MAXLEN; i += 512) Wl[i] = Bcur[i];
    for (int i = tid; i < 16 * HSTR; i += 512) Hi[i] = 0.f;
    __syncthreads();

    // masked softmax: one 64-lane wave per k
    {
        const int k  = tid >> 6;
        const int ln = tid & 63;
        float m = -3.4e38f;
        for (int l = ln; l < MAXLEN; l += 64) {
            float v = (l < len) ? Wl[k * MAXLEN + l] : NEGPAD;
            m = fmaxf(m, v);
        }
        #pragma unroll
        for (int off = 32; off >= 1; off >>= 1) m = fmaxf(m, __shfl_xor(m, off));
        float ssum = 0.f;
        for (int l = ln; l < MAXLEN; l += 64) {
            float v = (l < len) ? Wl[k * MAXLEN + l] : NEGPAD;
            ssum += __expf(v - m);
        }
        #pragma unroll
        for (int off = 32; off >= 1; off >>= 1) ssum += __shfl_xor(ssum, off);
        float inv = 1.f / ssum;
        for (int l = ln; l < MAXLEN; l += 64) {
            float v = (l < len) ? Wl[k * MAXLEN + l] : NEGPAD;
            Wl[k * MAXLEN + l] = __expf(v - m) * inv;
        }
    }
    __syncthreads();

    // pass 1: o = tid&255; lg groups interleave 4-l chunks; W==0 for l>=len
    const f16* lbh = LH + (size_t)b * (MAXLEN * OUTU);
    const f16* lbl = LL + (size_t)b * (MAXLEN * OUTU);
    const int o   = tid & 255;
    const int lg  = tid >> 8;
    const int lim = (len == 0) ? MAXLEN : len;
    float hk[KCAPS];
    #pragma unroll
    for (int k = 0; k < KCAPS; k++) hk[k] = 0.f;
    if (do_delta) {
        for (int l4 = lg * 4; l4 < lim; l4 += 8) {
            float v0 = (float)lbh[(l4 + 0) * OUTU + o] + (float)lbl[(l4 + 0) * OUTU + o];
            float v1 = (float)lbh[(l4 + 1) * OUTU + o] + (float)lbl[(l4 + 1) * OUTU + o];
            float v2 = (float)lbh[(l4 + 2) * OUTU + o] + (float)lbl[(l4 + 2) * OUTU + o];
            float v3 = (float)lbh[(l4 + 3) * OUTU + o] + (float)lbl[(l4 + 3) * OUTU + o];
            #pragma unroll
            for (int k = 0; k < KCAPS; k++) {
                const float4 w = *reinterpret_cast<const float4*>(&Wl[k * MAXLEN + l4]);
                hk[k] = fmaf(w.x, v0, hk[k]);
                hk[k] = fmaf(w.y, v1, hk[k]);
                hk[k] = fmaf(w.z, v2, hk[k]);
                hk[k] = fmaf(w.w, v3, hk[k]);
            }
        }
    } else {
        // last iteration: output-only; hi-plane precision suffices (5e-4 rel)
        for (int l4 = lg * 4; l4 < lim; l4 += 8) {
            float v0 = (float)lbh[(l4 + 0) * OUTU + o];
            float v1 = (float)lbh[(l4 + 1) * OUTU + o];
            float v2 = (float)lbh[(l4 + 2) * OUTU + o];
            float v3 = (float)lbh[(l4 + 3) * OUTU + o];
            #pragma unroll
            for (int k = 0; k < KCAPS; k++) {
                const float4 w = *reinterpret_cast<const float4*>(&Wl[k * MAXLEN + l4]);
                hk[k] = fmaf(w.x, v0, hk[k]);
                hk[k] = fmaf(w.y, v1, hk[k]);
                hk[k] = fmaf(w.z, v2, hk[k]);
                hk[k] = fmaf(w.w, v3, hk[k]);
            }
        }
    }
    if (lg == 1) {
        #pragma unroll
        for (int k = 0; k < KCAPS; k++) Sl[k * 256 + o] = hk[k];
    }
    __syncthreads();

    float scale = 0.f;
    if (lg == 0) {
        float n = 0.f;
        #pragma unroll
        for (int k = 0; k < KCAPS; k++) {
            hk[k] += Sl[k * 256 + o];
            n = fmaf(hk[k], hk[k], n);
        }
        scale = n / (1.f + n) * (1.f / sqrtf(n + 1e-9f));
        if (do_out) {
            #pragma unroll
            for (int k = 0; k < KCAPS; k++)
                out[((size_t)b * KCAPS + k) * OUTU + o] = scale * hk[k];
        }
    }
    if (!do_delta) return;

    if (lg == 0) {
        #pragma unroll
        for (int k = 0; k < KCAPS; k++) Hi[k * HSTR + o] = scale * hk[k];
    }
    __syncthreads();

    // pass 2 (MFMA): delta_T[l][k] = sum_o low[l][o]*high[k][o]; frags direct
    const int wave = tid >> 6, lane = tid & 63;
    const int nfr = (wave < 5) ? 2 : 1;
    f32x4 acc2[2];
    acc2[0] = (f32x4){0.f, 0.f, 0.f, 0.f};
    acc2[1] = (f32x4){0.f, 0.f, 0.f, 0.f};

    for (int ks = 0; ks < 8; ks++) {
        const int ob = ks * 32 + ((lane >> 4) * 8);
        f32x4 h0 = *reinterpret_cast<const f32x4*>(&Hi[(lane & 15) * HSTR + ob]);
        f32x4 h1 = *reinterpret_cast<const f32x4*>(&Hi[(lane & 15) * HSTR + ob + 4]);
        f16x8 bh, bl;
        #pragma unroll
        for (int j = 0; j < 4; j++) {
            f16 t = (f16)h0[j]; bh[j] = t; bl[j] = (f16)(h0[j] - (float)t);
        }
        #pragma unroll
        for (int j = 0; j < 4; j++) {
            f16 t = (f16)h1[j]; bh[4 + j] = t; bl[4 + j] = (f16)(h1[j] - (float)t);
        }
        for (int mi = 0; mi < nfr; mi++) {
            const int mf = wave + mi * 8;
            const int l  = mf * 16 + (lane & 15);      // may exceed 199: garbage row, unwritten
            const size_t aofs = (size_t)l * OUTU + ob;
            f16x8 ah = *reinterpret_cast<const f16x8*>(lbh + aofs);
            f16x8 al = *reinterpret_cast<const f16x8*>(lbl + aofs);
            acc2[mi] = __builtin_amdgcn_mfma_f32_16x16x32_f16(ah, bh, acc2[mi], 0, 0, 0);
            acc2[mi] = __builtin_amdgcn_mfma_f32_16x16x32_f16(al, bh, acc2[mi], 0, 0, 0);
            acc2[mi] = __builtin_amdgcn_mfma_f32_16x16x32_f16(ah, bl, acc2[mi], 0, 0, 0);
        }
    }
    const int kcol = lane & 15;
    if (kcol < KCAPS) {
        for (int mi = 0; mi < nfr; mi++) {
            const int mf = wave + mi * 8;
            const int lbase = mf * 16 + ((lane >> 4) * 4);
            #pragma unroll
            for (int r = 0; r < 4; r++) {
                const int l = lbase + r;
                if (l < MAXLEN)
                    partials[(size_t)(kcol * MAXLEN + l) * BATCH + b] = acc2[mi][r];
            }
        }
    }
}

// ---------------- B update ----------------
__global__ __launch_bounds__(256) void k_update(const float* __restrict__ partials,
                                                float* __restrict__ Bcur) {
    __shared__ float red[256];
    const int i   = blockIdx.x;
    const int tid = threadIdx.x;
    float s = 0.f;
    #pragma unroll
    for (int j = 0; j < BATCH / 256; j++) s += partials[(size_t)i * BATCH + tid + j * 256];
    red[tid] = s;
    __syncthreads();
    for (int st = 128; st > 0; st >>= 1) {
        if (tid < st) red[tid] += red[tid + st];
        __syncthreads();
    }
    if (tid == 0) Bcur[i] += red[0];
}

extern "C" void kernel_launch(void* const* d_in, const int* in_sizes, int n_in,
                              void* d_out, int out_size, void* d_ws, size_t ws_size,
                              hipStream_t stream) {
    const float* low = (const float*)d_in[0];
    const float* S   = (const float*)d_in[1];
    const float* Bm  = (const float*)d_in[2];
    const int*   seq = (const int*)d_in[3];
    float* out = (float*)d_out;

    char* ws = (char*)d_ws;
    f16*   LH       = (f16*)ws;                                // 104,857,600 B
    f16*   LL       = (f16*)(ws + 104857600);                  // 104,857,600 B
    float* Bcur     = (float*)(ws + 209715200);                // 6,400 B
    float* partials = (float*)(ws + 209721600);                // 6,553,600 B
    f16* Shi = (f16*)(ws + 209721600);                         // aliases partials (projection-only)
    f16* Slo = (f16*)(ws + 209721600 + 131072);

    k_prep<<<256, 256, 0, stream>>>(S, Bm, Shi, Slo, Bcur);
    k_project_mfma<<<3200, 256, 0, stream>>>(low, Shi, Slo, LH, LL);
    for (int it = 0; it < 3; it++) {
        int last = (it == 2);
        k_route<<<BATCH, 512, 0, stream>>>(Bcur, seq, LH, LL, partials, out,
                                           last ? 0 : 1, last ? 1 : 0);
        if (!last) k_update<<<KCAPS * MAXLEN, 256, 0, stream>>>(partials, Bcur);
    }
}

// Round 10
// 309.447 us; speedup vs baseline: 1.2526x; 1.1062x over previous
//
#include <hip/hip_runtime.h>

#define BATCH   1024
#define MAXLEN  200
#define KCAPS   8
#define INU     256
#define OUTU    256
#define NEGPAD  -65535.0f
#define HSTR    264   // T LDS row stride (floats)

typedef _Float16 f16;
typedef _Float16 f16x8 __attribute__((ext_vector_type(8)));
typedef float    f32x4 __attribute__((ext_vector_type(4)));

// ---------------- prep: Bcur copy + S transpose (ST[n][e] = S[e][n]) -------
__global__ void k_prep(const float* __restrict__ S, const float* __restrict__ Bm,
                       float* __restrict__ ST, float* __restrict__ Bcur) {
    int idx = blockIdx.x * 256 + threadIdx.x;    // 0 .. 65535
    if (idx < KCAPS * MAXLEN) Bcur[idx] = Bm[idx];
    int e = idx & 255, n = idx >> 8;
    ST[idx] = S[e * 256 + n];
}

// ---------------- per-iteration G kernel -----------------------------------
// Per batch b (1024 blocks x 512 thr):
//   W = softmax_l(mask(Bcur))                  [8,200]
//   G[k,e]  = sum_l W[k,l] * low[b,l,e]        (fp32, masked l -> half reads)
//   hp[k,o] = sum_e G[k,e] * S[e,o]            (fp32, S L2-resident)
//   high    = squash_k(hp)
//   do_T ? T[b,k,e] = sum_o high[k,o]*ST[o,e]  : out[b,k,o] = high[k,o]
__global__ __launch_bounds__(512) void k_G(const float* __restrict__ Bcur,
                                           const int*   __restrict__ seq_len,
                                           const float* __restrict__ low,
                                           const float* __restrict__ S,
                                           const float* __restrict__ ST,
                                           float*       __restrict__ Tg,
                                           float*       __restrict__ out,
                                           int do_T) {
    __shared__ float Wl[KCAPS * MAXLEN];   // 6.4 KB
    __shared__ float Gl[KCAPS * 256];      // 8 KB
    __shared__ float Hl[KCAPS * 256];      // 8 KB
    __shared__ float Sl[KCAPS * 256];      // 8 KB cross-group reduce slab
    const int b   = blockIdx.x;
    const int tid = threadIdx.x;
    const int len = seq_len[b];

    for (int i = tid; i < KCAPS * MAXLEN; i += 512) Wl[i] = Bcur[i];
    __syncthreads();

    // masked softmax: one 64-lane wave per k
    {
        const int k  = tid >> 6;
        const int ln = tid & 63;
        float m = -3.4e38f;
        for (int l = ln; l < MAXLEN; l += 64) {
            float v = (l < len) ? Wl[k * MAXLEN + l] : NEGPAD;
            m = fmaxf(m, v);
        }
        #pragma unroll
        for (int off = 32; off >= 1; off >>= 1) m = fmaxf(m, __shfl_xor(m, off));
        float ssum = 0.f;
        for (int l = ln; l < MAXLEN; l += 64) {
            float v = (l < len) ? Wl[k * MAXLEN + l] : NEGPAD;
            ssum += __expf(v - m);
        }
        #pragma unroll
        for (int off = 32; off >= 1; off >>= 1) ssum += __shfl_xor(ssum, off);
        float inv = 1.f / ssum;
        for (int l = ln; l < MAXLEN; l += 64) {
            float v = (l < len) ? Wl[k * MAXLEN + l] : NEGPAD;
            Wl[k * MAXLEN + l] = __expf(v - m) * inv;
        }
    }
    __syncthreads();

    const float* lb = low + (size_t)b * (MAXLEN * INU);
    const int o  = tid & 255;
    const int lg = tid >> 8;

    // phase B: G[k,o] = sum_l W[k,l]*low[l,o]; lg groups interleave 4-l chunks
    const int lim = (len == 0) ? MAXLEN : len;   // W==0 for l>=len when len>0
    float g[KCAPS];
    #pragma unroll
    for (int k = 0; k < KCAPS; k++) g[k] = 0.f;
    for (int l4 = lg * 4; l4 < lim; l4 += 8) {   // max l4=196 -> reads l<=199 safe
        float v0 = lb[(l4 + 0) * INU + o];
        float v1 = lb[(l4 + 1) * INU + o];
        float v2 = lb[(l4 + 2) * INU + o];
        float v3 = lb[(l4 + 3) * INU + o];
        #pragma unroll
        for (int k = 0; k < KCAPS; k++) {
            const float4 w = *reinterpret_cast<const float4*>(&Wl[k * MAXLEN + l4]);
            g[k] = fmaf(w.x, v0, g[k]);
            g[k] = fmaf(w.y, v1, g[k]);
            g[k] = fmaf(w.z, v2, g[k]);
            g[k] = fmaf(w.w, v3, g[k]);
        }
    }
    if (lg == 1) {
        #pragma unroll
        for (int k = 0; k < KCAPS; k++) Sl[k * 256 + o] = g[k];
    }
    __syncthreads();
    if (lg == 0) {
        #pragma unroll
        for (int k = 0; k < KCAPS; k++) Gl[k * 256 + o] = g[k] + Sl[k * 256 + o];
    }
    __syncthreads();

    // phase C: hp[k] = sum_e Gl[k,e]*S[e,o]  (e split across lg groups)
    float hp[KCAPS];
    #pragma unroll
    for (int k = 0; k < KCAPS; k++) hp[k] = 0.f;
    {
        const int e0 = lg * 128;
        for (int e = e0; e < e0 + 128; e++) {
            float s = S[e * 256 + o];              // coalesced; L2-hot
            #pragma unroll
            for (int k = 0; k < KCAPS; k++)
                hp[k] = fmaf(Gl[k * 256 + e], s, hp[k]);   // LDS broadcast
        }
    }
    if (lg == 1) {
        #pragma unroll
        for (int k = 0; k < KCAPS; k++) Sl[k * 256 + o] = hp[k];
    }
    __syncthreads();
    if (lg == 0) {
        float n = 0.f;
        #pragma unroll
        for (int k = 0; k < KCAPS; k++) {
            hp[k] += Sl[k * 256 + o];
            n = fmaf(hp[k], hp[k], n);
        }
        float scale = n / (1.f + n) * (1.f / sqrtf(n + 1e-9f));
        if (!do_T) {
            #pragma unroll
            for (int k = 0; k < KCAPS; k++)
                out[((size_t)b * KCAPS + k) * OUTU + o] = scale * hp[k];
        } else {
            #pragma unroll
            for (int k = 0; k < KCAPS; k++) Hl[k * 256 + o] = scale * hp[k];
        }
    }
    if (!do_T) return;
    __syncthreads();

    // phase D: T[k,e] = sum_n Hl[k,n]*ST[n,e]  (n split across lg groups)
    float t[KCAPS];
    #pragma unroll
    for (int k = 0; k < KCAPS; k++) t[k] = 0.f;
    {
        const int n0 = lg * 128;
        for (int n = n0; n < n0 + 128; n++) {
            float s = ST[n * 256 + o];             // coalesced; L2-hot
            #pragma unroll
            for (int k = 0; k < KCAPS; k++)
                t[k] = fmaf(Hl[k * 256 + n], s, t[k]);
        }
    }
    if (lg == 1) {
        #pragma unroll
        for (int k = 0; k < KCAPS; k++) Sl[k * 256 + o] = t[k];
    }
    __syncthreads();
    if (lg == 0) {
        #pragma unroll
        for (int k = 0; k < KCAPS; k++)
            Tg[(size_t)b * 2048 + k * 256 + o] = t[k] + Sl[k * 256 + o];
    }
}

// ---------------- delta kernel (MFMA): delta_T[l][k] = sum_e low[l,e]*T[k,e]
// Proven pass-2 structure; A-frags converted fp32->hi/lo on the fly.
__global__ __launch_bounds__(512) void k_delta(const float* __restrict__ Tg,
                                               const float* __restrict__ low,
                                               float*       __restrict__ partials) {
    __shared__ float Tl[16 * HSTR];        // rows 0..7 = T, 8..15 = 0
    const int b   = blockIdx.x;
    const int tid = threadIdx.x;

    for (int i = tid; i < 16 * HSTR; i += 512) {
        int row = i / HSTR, col = i - row * HSTR;
        Tl[i] = (row < KCAPS && col < 256) ? Tg[(size_t)b * 2048 + row * 256 + col] : 0.f;
    }
    __syncthreads();

    const float* lb = low + (size_t)b * (MAXLEN * INU);
    const int wave = tid >> 6, lane = tid & 63;
    const int nfr = (wave < 5) ? 2 : 1;    // 13 M-frags over 8 waves
    f32x4 acc2[2];
    acc2[0] = (f32x4){0.f, 0.f, 0.f, 0.f};
    acc2[1] = (f32x4){0.f, 0.f, 0.f, 0.f};

    for (int ks = 0; ks < 8; ks++) {
        const int ob = ks * 32 + ((lane >> 4) * 8);
        f32x4 h0 = *reinterpret_cast<const f32x4*>(&Tl[(lane & 15) * HSTR + ob]);
        f32x4 h1 = *reinterpret_cast<const f32x4*>(&Tl[(lane & 15) * HSTR + ob + 4]);
        f16x8 bh, bl;
        #pragma unroll
        for (int j = 0; j < 4; j++) {
            f16 t = (f16)h0[j]; bh[j] = t; bl[j] = (f16)(h0[j] - (float)t);
        }
        #pragma unroll
        for (int j = 0; j < 4; j++) {
            f16 t = (f16)h1[j]; bh[4 + j] = t; bl[4 + j] = (f16)(h1[j] - (float)t);
        }
        for (int mi = 0; mi < nfr; mi++) {
            const int mf = wave + mi * 8;
            const int l  = mf * 16 + (lane & 15);
            const int lc = (l < MAXLEN) ? l : (MAXLEN - 1);   // clamp: D rows >=200 unwritten
            const float* ap = lb + (size_t)lc * INU + ob;
            float4 v0 = *reinterpret_cast<const float4*>(ap);
            float4 v1 = *reinterpret_cast<const float4*>(ap + 4);
            f16x8 ah, al;
            ah[0] = (f16)v0.x; al[0] = (f16)(v0.x - (float)ah[0]);
            ah[1] = (f16)v0.y; al[1] = (f16)(v0.y - (float)ah[1]);
            ah[2] = (f16)v0.z; al[2] = (f16)(v0.z - (float)ah[2]);
            ah[3] = (f16)v0.w; al[3] = (f16)(v0.w - (float)ah[3]);
            ah[4] = (f16)v1.x; al[4] = (f16)(v1.x - (float)ah[4]);
            ah[5] = (f16)v1.y; al[5] = (f16)(v1.y - (float)ah[5]);
            ah[6] = (f16)v1.z; al[6] = (f16)(v1.z - (float)ah[6]);
            ah[7] = (f16)v1.w; al[7] = (f16)(v1.w - (float)ah[7]);
            acc2[mi] = __builtin_amdgcn_mfma_f32_16x16x32_f16(ah, bh, acc2[mi], 0, 0, 0);
            acc2[mi] = __builtin_amdgcn_mfma_f32_16x16x32_f16(al, bh, acc2[mi], 0, 0, 0);
            acc2[mi] = __builtin_amdgcn_mfma_f32_16x16x32_f16(ah, bl, acc2[mi], 0, 0, 0);
        }
    }
    const int kcol = lane & 15;
    if (kcol < KCAPS) {
        for (int mi = 0; mi < nfr; mi++) {
            const int mf = wave + mi * 8;
            const int lbase = mf * 16 + ((lane >> 4) * 4);
            #pragma unroll
            for (int r = 0; r < 4; r++) {
                const int l = lbase + r;
                if (l < MAXLEN)
                    partials[(size_t)(kcol * MAXLEN + l) * BATCH + b] = acc2[mi][r];
            }
        }
    }
}

// ---------------- B update: Bcur[i] += sum_b partials[i][b] ----------------
__global__ __launch_bounds__(256) void k_update(const float* __restrict__ partials,
                                                float* __restrict__ Bcur) {
    __shared__ float red[256];
    const int i   = blockIdx.x;
    const int tid = threadIdx.x;
    float s = 0.f;
    #pragma unroll
    for (int j = 0; j < BATCH / 256; j++) s += partials[(size_t)i * BATCH + tid + j * 256];
    red[tid] = s;
    __syncthreads();
    for (int st = 128; st > 0; st >>= 1) {
        if (tid < st) red[tid] += red[tid + st];
        __syncthreads();
    }
    if (tid == 0) Bcur[i] += red[0];
}

extern "C" void kernel_launch(void* const* d_in, const int* in_sizes, int n_in,
                              void* d_out, int out_size, void* d_ws, size_t ws_size,
                              hipStream_t stream) {
    const float* low = (const float*)d_in[0];
    const float* S   = (const float*)d_in[1];
    const float* Bm  = (const float*)d_in[2];
    const int*   seq = (const int*)d_in[3];
    float* out = (float*)d_out;

    char* ws = (char*)d_ws;
    float* Tg       = (float*)ws;                     // 1024*8*256*4 = 8,388,608 B
    float* Bcur     = (float*)(ws + 8388608);         // 6,400 B
    float* partials = (float*)(ws + 8395008);         // 1600*1024*4 = 6,553,600 B
    float* ST       = (float*)(ws + 14948608);        // 256*256*4 = 262,144 B

    k_prep<<<256, 256, 0, stream>>>(S, Bm, ST, Bcur);
    for (int it = 0; it < 3; it++) {
        int last = (it == 2);
        k_G<<<BATCH, 512, 0, stream>>>(Bcur, seq, low, S, ST, Tg, out, last ? 0 : 1);
        if (!last) {
            k_delta<<<BATCH, 512, 0, stream>>>(Tg, low, partials);
            k_update<<<KCAPS * MAXLEN, 256, 0, stream>>>(partials, Bcur);
        }
    }
}

// Round 11
// 232.464 us; speedup vs baseline: 1.6674x; 1.3312x over previous
//
#include <hip/hip_runtime.h>

#define BATCH   1024
#define MAXLEN  200
#define KCAPS   8
#define INU     256
#define OUTU    256
#define NEGPAD  -65535.0f
#define HSTR    264   // padded LDS row stride (floats)

typedef _Float16 f16;
typedef _Float16 f16x8 __attribute__((ext_vector_type(8)));
typedef float    f32x4 __attribute__((ext_vector_type(4)));

// ---------------- prep: Bcur copy + packed-frag S and S^T (hi/lo f16) ------
// packed idx = ((ks*16+nf)*64+lane)*8+j  <->  M[k = ks*32+(lane>>4)*8+j][n = nf*16+(lane&15)]
// phase C B-operand: M = S   (k-dim = e, n = o)  -> value S[k*256+n]
// phase D B-operand: M = S^T (k-dim = o, n = e)  -> value S[n*256+k]
__global__ void k_prep(const float* __restrict__ S, const float* __restrict__ Bm,
                       f16* __restrict__ Shi, f16* __restrict__ Slo,
                       f16* __restrict__ Thi, f16* __restrict__ Tlo,
                       float* __restrict__ Bcur) {
    int idx = blockIdx.x * 256 + threadIdx.x;    // 0 .. 65535
    if (idx < KCAPS * MAXLEN) Bcur[idx] = Bm[idx];
    int j    = idx & 7;
    int lane = (idx >> 3) & 63;
    int nf   = (idx >> 9) & 15;
    int ks   = idx >> 13;
    int k = ks * 32 + (lane >> 4) * 8 + j;
    int n = nf * 16 + (lane & 15);
    float vS = S[k * 256 + n];
    f16 hS = (f16)vS;
    Shi[idx] = hS;
    Slo[idx] = (f16)(vS - (float)hS);
    float vT = S[n * 256 + k];
    f16 hT = (f16)vT;
    Thi[idx] = hT;
    Tlo[idx] = (f16)(vT - (float)hT);
}

// ---------------- per-iteration G kernel -----------------------------------
// Per batch b (1024 blocks x 512 thr):
//   W = softmax_l(mask(Bcur))                      [8,200]   (wave per k)
//   G[k,e]  = sum_l W[k,l]*low[b,l,e]              (fp32 VALU, masked l)
//   hp[k,o] = sum_e G[k,e]*S[e,o]                  (MFMA split-f16, M=16 pad)
//   high    = squash_k(hp)                          (in-register)
//   do_T ? T[b,k,e] = sum_o high[k,o]*S[e,o]       (MFMA split-f16)
//        : out[b,k,o] = high[k,o]
__global__ __launch_bounds__(512) void k_G(const float* __restrict__ Bcur,
                                           const int*   __restrict__ seq_len,
                                           const float* __restrict__ low,
                                           const f16*   __restrict__ Shi,
                                           const f16*   __restrict__ Slo,
                                           const f16*   __restrict__ Thi,
                                           const f16*   __restrict__ Tlo,
                                           float*       __restrict__ Tg,
                                           float*       __restrict__ out,
                                           int do_T) {
    __shared__ float Wl[KCAPS * MAXLEN];   // 6.4 KB
    __shared__ float Gl[16 * HSTR];        // 16.9 KB (rows 8..15 zero)
    __shared__ float Hl[16 * HSTR];        // 16.9 KB (rows 8..15 zero)
    __shared__ float Sl[KCAPS * 256];      // 8 KB cross-group reduce slab
    const int b   = blockIdx.x;
    const int tid = threadIdx.x;
    const int len = seq_len[b];

    for (int i = tid; i < KCAPS * MAXLEN; i += 512) Wl[i] = Bcur[i];
    for (int i = tid; i < 16 * HSTR; i += 512) { Gl[i] = 0.f; Hl[i] = 0.f; }
    __syncthreads();

    // masked softmax: one 64-lane wave per k
    {
        const int k  = tid >> 6;
        const int ln = tid & 63;
        float m = -3.4e38f;
        for (int l = ln; l < MAXLEN; l += 64) {
            float v = (l < len) ? Wl[k * MAXLEN + l] : NEGPAD;
            m = fmaxf(m, v);
        }
        #pragma unroll
        for (int off = 32; off >= 1; off >>= 1) m = fmaxf(m, __shfl_xor(m, off));
        float ssum = 0.f;
        for (int l = ln; l < MAXLEN; l += 64) {
            float v = (l < len) ? Wl[k * MAXLEN + l] : NEGPAD;
            ssum += __expf(v - m);
        }
        #pragma unroll
        for (int off = 32; off >= 1; off >>= 1) ssum += __shfl_xor(ssum, off);
        float inv = 1.f / ssum;
        for (int l = ln; l < MAXLEN; l += 64) {
            float v = (l < len) ? Wl[k * MAXLEN + l] : NEGPAD;
            Wl[k * MAXLEN + l] = __expf(v - m) * inv;
        }
    }
    __syncthreads();

    const float* lb = low + (size_t)b * (MAXLEN * INU);
    const int o  = tid & 255;
    const int lg = tid >> 8;

    // phase B: G[k,o] = sum_l W[k,l]*low[l,o]; lg groups interleave 4-l chunks
    const int lim = (len == 0) ? MAXLEN : len;   // W==0 for l>=len when len>0
    {
        float g[KCAPS];
        #pragma unroll
        for (int k = 0; k < KCAPS; k++) g[k] = 0.f;
        for (int l4 = lg * 4; l4 < lim; l4 += 8) {   // max l4=196 -> reads l<=199 safe
            float v0 = lb[(l4 + 0) * INU + o];
            float v1 = lb[(l4 + 1) * INU + o];
            float v2 = lb[(l4 + 2) * INU + o];
            float v3 = lb[(l4 + 3) * INU + o];
            #pragma unroll
            for (int k = 0; k < KCAPS; k++) {
                const float4 w = *reinterpret_cast<const float4*>(&Wl[k * MAXLEN + l4]);
                g[k] = fmaf(w.x, v0, g[k]);
                g[k] = fmaf(w.y, v1, g[k]);
                g[k] = fmaf(w.z, v2, g[k]);
                g[k] = fmaf(w.w, v3, g[k]);
            }
        }
        if (lg == 1) {
            #pragma unroll
            for (int k = 0; k < KCAPS; k++) Sl[k * 256 + o] = g[k];
        }
        __syncthreads();
        if (lg == 0) {
            #pragma unroll
            for (int k = 0; k < KCAPS; k++) Gl[k * HSTR + o] = g[k] + Sl[k * 256 + o];
        }
    }
    __syncthreads();

    // phase C (MFMA): hp[k][o] = sum_e G[k][e]*S[e][o].  A = Gl rows (16, 8 pad),
    // B = packed Shi/Slo. Wave wv covers nf = 2wv, 2wv+1.
    const int wv = tid >> 6, lane = tid & 63;
    const int r15 = lane & 15, q = lane >> 4;
    f32x4 aC[2];
    aC[0] = (f32x4){0.f, 0.f, 0.f, 0.f};
    aC[1] = (f32x4){0.f, 0.f, 0.f, 0.f};
    #pragma unroll
    for (int ks = 0; ks < 8; ks++) {
        const float* gp = &Gl[r15 * HSTR + ks * 32 + q * 8];
        f32x4 a0 = *reinterpret_cast<const f32x4*>(gp);
        f32x4 a1 = *reinterpret_cast<const f32x4*>(gp + 4);
        f16x8 ah, al;
        #pragma unroll
        for (int j = 0; j < 4; j++) {
            f16 t = (f16)a0[j]; ah[j] = t; al[j] = (f16)(a0[j] - (float)t);
        }
        #pragma unroll
        for (int j = 0; j < 4; j++) {
            f16 t = (f16)a1[j]; ah[4 + j] = t; al[4 + j] = (f16)(a1[j] - (float)t);
        }
        #pragma unroll
        for (int i = 0; i < 2; i++) {
            const int nf = wv * 2 + i;
            f16x8 bh = *reinterpret_cast<const f16x8*>(Shi + (ks * 16 + nf) * 512 + lane * 8);
            f16x8 bl = *reinterpret_cast<const f16x8*>(Slo + (ks * 16 + nf) * 512 + lane * 8);
            aC[i] = __builtin_amdgcn_mfma_f32_16x16x32_f16(ah, bh, aC[i], 0, 0, 0);
            aC[i] = __builtin_amdgcn_mfma_f32_16x16x32_f16(al, bh, aC[i], 0, 0, 0);
            aC[i] = __builtin_amdgcn_mfma_f32_16x16x32_f16(ah, bl, aC[i], 0, 0, 0);
        }
    }
    // squash: thread holds hp[k=q*4+r][o=(2wv+i)*16+r15]; k<8 lives in q=0,1
    {
        float n0 = aC[0][0]*aC[0][0] + aC[0][1]*aC[0][1] + aC[0][2]*aC[0][2] + aC[0][3]*aC[0][3];
        float n1 = aC[1][0]*aC[1][0] + aC[1][1]*aC[1][1] + aC[1][2]*aC[1][2] + aC[1][3]*aC[1][3];
        n0 += __shfl_xor(n0, 16);
        n1 += __shfl_xor(n1, 16);
        float s0 = n0 / (1.f + n0) * (1.f / sqrtf(n0 + 1e-9f));
        float s1 = n1 / (1.f + n1) * (1.f / sqrtf(n1 + 1e-9f));
        if (q < 2) {
            if (!do_T) {
                #pragma unroll
                for (int r = 0; r < 4; r++) {
                    out[((size_t)b * KCAPS + q * 4 + r) * OUTU + (wv * 2 + 0) * 16 + r15] = s0 * aC[0][r];
                    out[((size_t)b * KCAPS + q * 4 + r) * OUTU + (wv * 2 + 1) * 16 + r15] = s1 * aC[1][r];
                }
            } else {
                #pragma unroll
                for (int r = 0; r < 4; r++) {
                    Hl[(q * 4 + r) * HSTR + (wv * 2 + 0) * 16 + r15] = s0 * aC[0][r];
                    Hl[(q * 4 + r) * HSTR + (wv * 2 + 1) * 16 + r15] = s1 * aC[1][r];
                }
            }
        }
    }
    if (!do_T) return;
    __syncthreads();

    // phase D (MFMA): T[k][e] = sum_o H[k][o]*S[e][o].  A = Hl, B = packed Thi/Tlo.
    f32x4 aD[2];
    aD[0] = (f32x4){0.f, 0.f, 0.f, 0.f};
    aD[1] = (f32x4){0.f, 0.f, 0.f, 0.f};
    #pragma unroll
    for (int ks = 0; ks < 8; ks++) {
        const float* hp = &Hl[r15 * HSTR + ks * 32 + q * 8];
        f32x4 a0 = *reinterpret_cast<const f32x4*>(hp);
        f32x4 a1 = *reinterpret_cast<const f32x4*>(hp + 4);
        f16x8 ah, al;
        #pragma unroll
        for (int j = 0; j < 4; j++) {
            f16 t = (f16)a0[j]; ah[j] = t; al[j] = (f16)(a0[j] - (float)t);
        }
        #pragma unroll
        for (int j = 0; j < 4; j++) {
            f16 t = (f16)a1[j]; ah[4 + j] = t; al[4 + j] = (f16)(a1[j] - (float)t);
        }
        #pragma unroll
        for (int i = 0; i < 2; i++) {
            const int nf = wv * 2 + i;
            f16x8 bh = *reinterpret_cast<const f16x8*>(Thi + (ks * 16 + nf) * 512 + lane * 8);
            f16x8 bl = *reinterpret_cast<const f16x8*>(Tlo + (ks * 16 + nf) * 512 + lane * 8);
            aD[i] = __builtin_amdgcn_mfma_f32_16x16x32_f16(ah, bh, aD[i], 0, 0, 0);
            aD[i] = __builtin_amdgcn_mfma_f32_16x16x32_f16(al, bh, aD[i], 0, 0, 0);
            aD[i] = __builtin_amdgcn_mfma_f32_16x16x32_f16(ah, bl, aD[i], 0, 0, 0);
        }
    }
    if (q < 2) {
        #pragma unroll
        for (int r = 0; r < 4; r++) {
            Tg[(size_t)b * 2048 + (q * 4 + r) * 256 + (wv * 2 + 0) * 16 + r15] = aD[0][r];
            Tg[(size_t)b * 2048 + (q * 4 + r) * 256 + (wv * 2 + 1) * 16 + r15] = aD[1][r];
        }
    }
}

// ---------------- delta kernel (MFMA): delta_T[l][k] = sum_e low[l,e]*T[k,e]
__global__ __launch_bounds__(512) void k_delta(const float* __restrict__ Tg,
                                               const float* __restrict__ low,
                                               float*       __restrict__ partials) {
    __shared__ float Tl[16 * HSTR];        // rows 0..7 = T, 8..15 = 0
    const int b   = blockIdx.x;
    const int tid = threadIdx.x;

    for (int i = tid; i < 16 * HSTR; i += 512) {
        int row = i / HSTR, col = i - row * HSTR;
        Tl[i] = (row < KCAPS && col < 256) ? Tg[(size_t)b * 2048 + row * 256 + col] : 0.f;
    }
    __syncthreads();

    const float* lb = low + (size_t)b * (MAXLEN * INU);
    const int wave = tid >> 6, lane = tid & 63;
    const int nfr = (wave < 5) ? 2 : 1;    // 13 M-frags over 8 waves
    f32x4 acc2[2];
    acc2[0] = (f32x4){0.f, 0.f, 0.f, 0.f};
    acc2[1] = (f32x4){0.f, 0.f, 0.f, 0.f};

    for (int ks = 0; ks < 8; ks++) {
        const int ob = ks * 32 + ((lane >> 4) * 8);
        f32x4 h0 = *reinterpret_cast<const f32x4*>(&Tl[(lane & 15) * HSTR + ob]);
        f32x4 h1 = *reinterpret_cast<const f32x4*>(&Tl[(lane & 15) * HSTR + ob + 4]);
        f16x8 bh, bl;
        #pragma unroll
        for (int j = 0; j < 4; j++) {
            f16 t = (f16)h0[j]; bh[j] = t; bl[j] = (f16)(h0[j] - (float)t);
        }
        #pragma unroll
        for (int j = 0; j < 4; j++) {
            f16 t = (f16)h1[j]; bh[4 + j] = t; bl[4 + j] = (f16)(h1[j] - (float)t);
        }
        for (int mi = 0; mi < nfr; mi++) {
            const int mf = wave + mi * 8;
            const int l  = mf * 16 + (lane & 15);
            const int lc = (l < MAXLEN) ? l : (MAXLEN - 1);   // clamp: D rows >=200 unwritten
            const float* ap = lb + (size_t)lc * INU + ob;
            float4 v0 = *reinterpret_cast<const float4*>(ap);
            float4 v1 = *reinterpret_cast<const float4*>(ap + 4);
            f16x8 ah, al;
            ah[0] = (f16)v0.x; al[0] = (f16)(v0.x - (float)ah[0]);
            ah[1] = (f16)v0.y; al[1] = (f16)(v0.y - (float)ah[1]);
            ah[2] = (f16)v0.z; al[2] = (f16)(v0.z - (float)ah[2]);
            ah[3] = (f16)v0.w; al[3] = (f16)(v0.w - (float)ah[3]);
            ah[4] = (f16)v1.x; al[4] = (f16)(v1.x - (float)ah[4]);
            ah[5] = (f16)v1.y; al[5] = (f16)(v1.y - (float)ah[5]);
            ah[6] = (f16)v1.z; al[6] = (f16)(v1.z - (float)ah[6]);
            ah[7] = (f16)v1.w; al[7] = (f16)(v1.w - (float)ah[7]);
            acc2[mi] = __builtin_amdgcn_mfma_f32_16x16x32_f16(ah, bh, acc2[mi], 0, 0, 0);
            acc2[mi] = __builtin_amdgcn_mfma_f32_16x16x32_f16(al, bh, acc2[mi], 0, 0, 0);
            acc2[mi] = __builtin_amdgcn_mfma_f32_16x16x32_f16(ah, bl, acc2[mi], 0, 0, 0);
        }
    }
    const int kcol = lane & 15;
    if (kcol < KCAPS) {
        for (int mi = 0; mi < nfr; mi++) {
            const int mf = wave + mi * 8;
            const int lbase = mf * 16 + ((lane >> 4) * 4);
            #pragma unroll
            for (int r = 0; r < 4; r++) {
                const int l = lbase + r;
                if (l < MAXLEN)
                    partials[(size_t)(kcol * MAXLEN + l) * BATCH + b] = acc2[mi][r];
            }
        }
    }
}

// ---------------- B update: Bcur[i] += sum_b partials[i][b] ----------------
__global__ __launch_bounds__(256) void k_update(const float* __restrict__ partials,
                                                float* __restrict__ Bcur) {
    __shared__ float red[256];
    const int i   = blockIdx.x;
    const int tid = threadIdx.x;
    float s = 0.f;
    #pragma unroll
    for (int j = 0; j < BATCH / 256; j++) s += partials[(size_t)i * BATCH + tid + j * 256];
    red[tid] = s;
    __syncthreads();
    for (int st = 128; st > 0; st >>= 1) {
        if (tid < st) red[tid] += red[tid + st];
        __syncthreads();
    }
    if (tid == 0) Bcur[i] += red[0];
}

extern "C" void kernel_launch(void* const* d_in, const int* in_sizes, int n_in,
                              void* d_out, int out_size, void* d_ws, size_t ws_size,
                              hipStream_t stream) {
    const float* low = (const float*)d_in[0];
    const float* S   = (const float*)d_in[1];
    const float* Bm  = (const float*)d_in[2];
    const int*   seq = (const int*)d_in[3];
    float* out = (float*)d_out;

    char* ws = (char*)d_ws;
    float* Tg       = (float*)ws;                     // 8,388,608 B
    float* Bcur     = (float*)(ws + 8388608);         // 6,400 B
    float* partials = (float*)(ws + 8395008);         // 6,553,600 B
    f16*   Shi      = (f16*)(ws + 14948608);          // 131,072 B
    f16*   Slo      = (f16*)(ws + 15079680);          // 131,072 B
    f16*   Thi      = (f16*)(ws + 15210752);          // 131,072 B
    f16*   Tlo      = (f16*)(ws + 15341824);          // 131,072 B

    k_prep<<<256, 256, 0, stream>>>(S, Bm, Shi, Slo, Thi, Tlo, Bcur);
    for (int it = 0; it < 3; it++) {
        int last = (it == 2);
        k_G<<<BATCH, 512, 0, stream>>>(Bcur, seq, low, Shi, Slo, Thi, Tlo, Tg, out, last ? 0 : 1);
        if (!last) {
            k_delta<<<BATCH, 512, 0, stream>>>(Tg, low, partials);
            k_update<<<KCAPS * MAXLEN, 256, 0, stream>>>(partials, Bcur);
        }
    }
}